// Round 7
// baseline (160.317 us; speedup 1.0000x reference)
//
#include <hip/hip_runtime.h>
#include <math.h>

// R6 (NT loads, fused, 44.6us) + tail amortization:
//  - Each block streams CHUNKS=2 chunks of 32 items (8 items/wave/chunk),
//    no barrier between chunks; Gram sums parked in LDS.
//  - Reduce-scatter (14 f64 shuffles) instead of full butterfly (45):
//    lane s of each 8-lane group ends owning Gram sums {k,k+1},
//    k = ((s&1)<<3)|((s&2)<<1)|((s&4)>>1), writes both to LDS directly.
//  - ONE __syncthreads, then phase 2 with 64 active lanes, 1 item each.
// All math fp64 (Cantor chain amplifies seed error ~3^8).

typedef float f32x4 __attribute__((ext_vector_type(4)));

__device__ __forceinline__ constexpr int gidx(int i, int j) {
    return i * 5 - i * (i - 1) / 2 + (j - i);   // upper-tri (i<=j) -> [0,15)
}

__global__ __launch_bounds__(256, 4) void fingerprint_kernel(
    const float* __restrict__ pent, float* __restrict__ out, int nItems)
{
    // Transposed: lds_g[q][slot], slot in [0,64). 8 KiB.
    __shared__ double lds_g[16][64];

    const int tid  = threadIdx.x;
    const int wave = tid >> 6;
    const int lane = tid & 63;
    const int grp  = lane >> 3;   // group (item) within wave
    const int s    = lane & 7;    // slice within item
    // Gram indices this lane will own after reduce-scatter:
    const int k = ((s & 1) << 3) | ((s & 2) << 1) | ((s & 4) >> 1);

    const long base = (long)blockIdx.x * 64;

#pragma unroll
    for (int c = 0; c < 2; ++c) {
        const int slot = c * 32 + wave * 8 + grp;
        long item  = base + slot;
        long itemC = item < nItems ? item : (long)nItems - 1;

        const f32x4* __restrict__ p =
            reinterpret_cast<const f32x4*>(pent + itemC * 640L);

        // 20 x global_load_dwordx4 nt; lanes s=0..7 cover a contiguous 128B
        // chunk per (v,j) -> fully coalesced; stream read once, skip caches.
        f32x4 f[5][4];
#pragma unroll
        for (int v = 0; v < 5; ++v)
#pragma unroll
            for (int j = 0; j < 4; ++j)
                f[v][j] = __builtin_nontemporal_load(&p[v * 32 + j * 8 + s]);

        const float* fp = reinterpret_cast<const float*>(f);

        double g[16];
#pragma unroll
        for (int q = 0; q < 16; ++q) g[q] = 0.0;

#pragma unroll
        for (int t = 0; t < 16; ++t) {       // this lane's 16 dims
            double a[5];
#pragma unroll
            for (int v = 0; v < 5; ++v)
                a[v] = (double)fp[v * 16 + t];
            int q = 0;
#pragma unroll
            for (int i = 0; i < 5; ++i)
#pragma unroll
                for (int j = i; j < 5; ++j) {
                    g[q] = fma(a[i], a[j], g[q]);
                    ++q;
                }
        }

        // 3-stage reduce-scatter within the 8-lane group (masks 1,2,4).
        // Lane-dependent choice on VALUES only; indices static.
        {
            const bool b = (s & 1) != 0;
#pragma unroll
            for (int i = 0; i < 8; ++i) {
                double lo = g[i], hi = g[i + 8];
                double recv = __shfl_xor(b ? lo : hi, 1, 64);
                g[i] = (b ? hi : lo) + recv;
            }
        }
        {
            const bool b = (s & 2) != 0;
#pragma unroll
            for (int i = 0; i < 4; ++i) {
                double lo = g[i], hi = g[i + 4];
                double recv = __shfl_xor(b ? lo : hi, 2, 64);
                g[i] = (b ? hi : lo) + recv;
            }
        }
        {
            const bool b = (s & 4) != 0;
#pragma unroll
            for (int i = 0; i < 2; ++i) {
                double lo = g[i], hi = g[i + 2];
                double recv = __shfl_xor(b ? lo : hi, 4, 64);
                g[i] = (b ? hi : lo) + recv;
            }
        }
        // lane owns sums {k, k+1} in g[0], g[1]; park in LDS (all lanes).
        lds_g[k][slot]     = g[0];
        lds_g[k + 1][slot] = g[1];
    }

    __syncthreads();

    // ---- Phase 2: 64 active lanes, one item per lane ----
    if (tid < 64) {
        const long item2 = base + tid;

        double h[15];
#pragma unroll
        for (int q = 0; q < 15; ++q) h[q] = lds_g[q][tid];

        // Edge statistics over the 10 pairwise distances (ddof=1).
        double e[10];
        double se = 0.0;
        {
            int q = 0;
#pragma unroll
            for (int i = 0; i < 5; ++i)
#pragma unroll
                for (int j = i + 1; j < 5; ++j) {
                    double d2 = fma(-2.0, h[gidx(i, j)],
                                    h[gidx(i, i)] + h[gidx(j, j)]);
                    e[q] = sqrt(d2);
                    se += e[q];
                    ++q;
                }
        }
        double meanE = se * 0.1;
        double ve = 0.0;
#pragma unroll
        for (int q = 0; q < 10; ++q) {
            double d = e[q] - meanE;
            ve = fma(d, d, ve);
        }
        double stdE = sqrt(ve / 9.0);

        // Row sums S[i] = sum_j G[i][j], total T.
        double S[5], T = 0.0;
#pragma unroll
        for (int i = 0; i < 5; ++i) {
            double si = 0.0;
#pragma unroll
            for (int j = 0; j < 5; ++j) {
                int a = i < j ? i : j;
                int b = i < j ? j : i;
                si += h[gidx(a, b)];
            }
            S[i] = si;
            T += si;
        }

        // Vertex spread (ddof=1 over 5 centroid distances).
        double scd = 0.0, cd[5];
#pragma unroll
        for (int v = 0; v < 5; ++v) {
            double c2 = fma(-0.4, S[v], h[gidx(v, v)]) + 0.04 * T;
            cd[v] = (c2 > 0.0) ? sqrt(c2) : 0.0;
            scd += cd[v];
        }
        double meanC = scd * 0.2;
        double vc = 0.0;
#pragma unroll
        for (int v = 0; v < 5; ++v) {
            double d = cd[v] - meanC;
            vc = fma(d, d, vc);
        }
        double spread = sqrt(vc * 0.25);

        // W[pq] = (x_p - x_0)·(x_q - x_0), p,q in 1..4 (PSD) ->
        // det M6 = -16 det W; volume^2 = det W / 576.
        double W[4][4];
#pragma unroll
        for (int pi = 0; pi < 4; ++pi)
#pragma unroll
            for (int qi = 0; qi < 4; ++qi) {
                int lo = (pi < qi ? pi : qi) + 1;
                int hi = (pi < qi ? qi : pi) + 1;
                W[pi][qi] = h[gidx(lo, hi)] - h[gidx(0, qi + 1)]
                          - h[gidx(0, pi + 1)] + h[gidx(0, 0)];
            }

        double det = 1.0;
#pragma unroll
        for (int kk = 0; kk < 4; ++kk) {
            double pv = W[kk][kk];
            det *= pv;
            double inv = (pv != 0.0) ? 1.0 / pv : 0.0;
#pragma unroll
            for (int r = kk + 1; r < 4; ++r) {
                double fac = W[r][kk] * inv;
#pragma unroll
                for (int cc = kk + 1; cc < 4; ++cc)
                    W[r][cc] = fma(-fac, W[kk][cc], W[r][cc]);
            }
        }

        double v2 = det / 576.0;
        double volume = (v2 > 0.0) ? sqrt(v2) : 0.0;

        double vn = 1.0 / (1.0 + exp(-10.0 * volume));
        double er = 1.0 / (1.0 + exp(-(stdE / (meanE + 1e-6))));
        double sn = 1.0 / (1.0 + exp(-spread));

        double seed = 0.4 * vn + 0.3 * er + 0.3 * sn;
        seed = fmin(fmax(seed, 1e-6), 1.0 - 1e-6);
        double drift = (vn + er + sn) * 0.01;

        double x = seed, cv = 0.0, factor = 0.5;
#pragma unroll
        for (int kk = 0; kk < 8; ++kk) {
            double xs = x * 3.0;
            double dg = floor(xs);
            double fr = xs - dg;
            cv += (dg == 2.0) ? factor : 0.0;
            factor *= 0.5;
            x = fmin(fmax(fr + drift, 1e-6), 1.0 - 1e-6);
        }
        cv = fmin(fmax(cv, 0.0), 1.0);

        if (item2 < nItems)
            __builtin_nontemporal_store((float)cv, &out[item2]);
    }
}

extern "C" void kernel_launch(void* const* d_in, const int* in_sizes, int n_in,
                              void* d_out, int out_size, void* d_ws, size_t ws_size,
                              hipStream_t stream) {
    const float* pent = (const float*)d_in[0];
    float* out = (float*)d_out;
    int nItems = in_sizes[0] / 640;            // 5*128 floats per item
    int blocks = (nItems + 63) / 64;           // 64 items per 256-thread block
    hipLaunchKernelGGL(fingerprint_kernel, dim3(blocks), dim3(256), 0, stream,
                       pent, out, nItems);
}